// Round 1
// baseline (339.103 us; speedup 1.0000x reference)
//
#include <hip/hip_runtime.h>

// support[1::2, 1::2] of an 8192x8192 fp32 matrix -> 4096x4096 fp32.
// Memory-bound: ~128 MiB fetch (odd rows only) + 64 MiB write.

#define IN_N 8192
#define OUT_N 4096

__global__ __launch_bounds__(256) void coarse_slice_kernel(
    const float* __restrict__ in, float* __restrict__ out) {
    // Each thread writes 4 consecutive output floats (one float4).
    const size_t t = (size_t)blockIdx.x * blockDim.x + threadIdx.x;
    const size_t o = t << 2;                  // flat output index (multiple of 4)
    const int r = (int)(o >> 12);             // output row   (o / 4096)
    const int c = (int)(o & (OUT_N - 1));     // output col   (multiple of 4)

    // Input row 2r+1, starting input col 2c (we want odd cols 2c+1..2c+7).
    const float* src = in + (size_t)(2 * r + 1) * IN_N + (size_t)(2 * c);
    const float4 a = ((const float4*)src)[0]; // cols 2c .. 2c+3
    const float4 b = ((const float4*)src)[1]; // cols 2c+4 .. 2c+7

    ((float4*)out)[t] = make_float4(a.y, a.w, b.y, b.w);
}

extern "C" void kernel_launch(void* const* d_in, const int* in_sizes, int n_in,
                              void* d_out, int out_size, void* d_ws, size_t ws_size,
                              hipStream_t stream) {
    const float* in = (const float*)d_in[0];
    float* out = (float*)d_out;

    // 4096*4096 outputs / 4 per thread = 4,194,304 threads = 16384 blocks of 256.
    const int threads = 256;
    const int blocks = (OUT_N * OUT_N / 4) / threads;
    coarse_slice_kernel<<<blocks, threads, 0, stream>>>(in, out);
}